// Round 9
// baseline (362.780 us; speedup 1.0000x reference)
//
#include <hip/hip_runtime.h>
#include <cmath>

// Problem constants (from reference)
#define NB 4
#define NP 8192            // 2^13 points per batch
#define NE 262144          // 2^18 edges per batch
#define NCIN 32
#define NCOUT 32
#define NH 16
#define GAMMA 4.0f
#define NFEAT (NB * NP * NCIN)      // 1,048,576 floats (4 MB)
#define NOUT  (NB * NP * NCOUT)     // 1,048,576 floats (4 MB)
#define TILES_PER_BATCH (NE / 64)
#define NXCD 8
#define SLICE (NP * NCOUT)          // 262,144 floats = 1 MB: one batch's out rows
#define QCAP 8192                   // 16-edge chunks per queue (2 queues/batch)
#define SUPER 8                     // chunks per pop: 8 chunks = 128 edges
#define NSUPER (QCAP / SUPER)       // 1024 super-chunks per queue

typedef _Float16 half8 __attribute__((ext_vector_type(8)));
typedef float floatx4 __attribute__((ext_vector_type(4)));

// ---------------------------------------------------------------------------
// Prep: zero partial slices (8 MB) + overflow (4 MB) + queue counters, and
// build the f16 feature table. All streaming, ~8 us.
// ws layout: partial[8][1MB] | ovf[4MB] | f16[2MB] | qcnt[8*16 ints]
// ---------------------------------------------------------------------------
__global__ __launch_bounds__(256)
void prep_kernel(const float* __restrict__ features,
                 _Float16* __restrict__ f16t,
                 floatx4* __restrict__ zero4,     // partial+ovf = 786432 float4
                 int* __restrict__ qcnt)
{
    const int i = blockIdx.x * blockDim.x + threadIdx.x;    // 0 .. 262143
    const floatx4 z = {0.f, 0.f, 0.f, 0.f};
    #pragma unroll
    for (int k = 0; k < 3; ++k)
        zero4[(long)k * 262144 + i] = z;

    if (i < 128) qcnt[i] = 0;

    if (i < NFEAT / 8) {                        // f32 -> f16 table
        const floatx4* src = (const floatx4*)features + (long)i * 2;
        floatx4 v0 = src[0], v1 = src[1];
        half8 h;
        h[0] = (_Float16)v0[0]; h[1] = (_Float16)v0[1];
        h[2] = (_Float16)v0[2]; h[3] = (_Float16)v0[3];
        h[4] = (_Float16)v1[0]; h[5] = (_Float16)v1[1];
        h[6] = (_Float16)v1[2]; h[7] = (_Float16)v1[3];
        *((half8*)f16t + i) = h;
    }
}

// cvt-only variant for the fallback path.
__global__ __launch_bounds__(256)
void cvt_f16_kernel(const float* __restrict__ features, _Float16* __restrict__ f16t)
{
    const int i = blockIdx.x * blockDim.x + threadIdx.x;    // 0 .. 131071
    const floatx4* src = (const floatx4*)features + (long)i * 2;
    floatx4 v0 = src[0], v1 = src[1];
    half8 h;
    h[0] = (_Float16)v0[0]; h[1] = (_Float16)v0[1];
    h[2] = (_Float16)v0[2]; h[3] = (_Float16)v0[3];
    h[4] = (_Float16)v1[0]; h[5] = (_Float16)v1[1];
    h[6] = (_Float16)v1[2]; h[7] = (_Float16)v1[3];
    *((half8*)f16t + i) = h;
}

// ---------------------------------------------------------------------------
// Reduce: out = scale * (slice[2b] + slice[2b+1] + ovf).  16 MB streaming.
// ---------------------------------------------------------------------------
__global__ __launch_bounds__(256)
void reduce_kernel(const floatx4* __restrict__ partial4,   // 8 slices
                   const floatx4* __restrict__ ovf4,       // out-shaped
                   const int* __restrict__ n_norm_p,
                   floatx4* __restrict__ out4)
{
    const int i = blockIdx.x * blockDim.x + threadIdx.x;    // 0 .. 262143
    const int nn = n_norm_p[0];
    const float scale = (nn > 0) ? rsqrtf((float)nn) : 1.0f;
    const int b = i >> 16;                                   // 65536 float4/batch
    const int li = i & 65535;                                // idx within slice
    floatx4 s = partial4[(long)(2 * b) * 65536 + li]
              + partial4[(long)(2 * b + 1) * 65536 + li]
              + ovf4[i];
    out4[i] = s * scale;
}

// ---------------------------------------------------------------------------
// Main kernel: per-XCD work queues keyed on hardware XCC_ID.
//
// Bisect history: R7 (per-wave 16-edge pops) -> FETCH 13 MB but pop-chain
// serialized (337 us). R8 (per-block 1024-edge pops) -> pops cheap but
// FETCH back to 445 MB. Hypothesis: R8's waves streamed 256 CONTIGUOUS
// edges (1-3 KB sequential nt runs), which L2 allocates/prefetches,
// continuously evicting the hot feature+partial lines; R7's scattered
// 64-192 B chunk reads did not. R9 keeps block-level pops (cheap) but:
//   SUPER = 8 (128 edges/pop) and waves take INTERLEAVED chunks
//   (c = sc*8 + it*4 + wv) -> per-wave stream reads are 64-192 B
//   scattered, exactly R7's shape.
//
// Queue x holds only batch (x>>1)'s chunks; blocks pop the queue of the XCD
// they PHYSICALLY run on (s_getreg XCC_ID, m09). Hot set per XCD: 512 KB
// f16 features + 1 MB private partial slice. Local scatter: workgroup-scope
// (L2-executed) atomics. Steal path (dispatch-independence insurance):
// device-scope atomics into a separate overflow buffer.
//
// GEMM view: msg[e, o] = sum_k Z[e,k] * W2T[k,o],  k = h*32 + i, K = 512
//   Z[e, h*32+i] = rbf_h(e) * x_src[e][i]
// MFMA f32_16x16x32_f16 layouts (HW-verified, learn_hip m89/m91):
//   A: lane holds A[m=lane&15][k_local=(lane>>4)*8+j], j=0..7
//   B: lane holds B[k_local][n=lane&15]
//   D: lane holds D[row=(lane>>4)*4+rr][col=m]
// ---------------------------------------------------------------------------
__global__ __launch_bounds__(256, 4)
void pconv_queue_kernel(const _Float16* __restrict__ feat16,
                        const float* __restrict__ edge_vec,
                        const float* __restrict__ W,
                        const float* __restrict__ mu,
                        const int* __restrict__ edge_src,
                        const int* __restrict__ edge_dst,
                        float* __restrict__ partial,   // 8 x 1 MB slices
                        float* __restrict__ ovf,       // out-shaped, 4 MB
                        int* __restrict__ qcnt)        // 8 counters, 64B apart
{
    __shared__ _Float16 wsw[16 * 2 * 64 * 8];   // 32 KiB, B-fragment order
    __shared__ float mus[16];
    __shared__ int sc_sh;

    const int tid = threadIdx.x;
    for (int idx = tid; idx < 16384; idx += 256) {
        int j = idx & 7;
        int l = (idx >> 3) & 63;
        int u = (idx >> 9) & 1;
        int s = idx >> 10;
        int n = (l & 15) + (u << 4);          // output channel o
        int i = ((l >> 4) << 3) | j;          // input channel
        wsw[idx] = (_Float16)W[(s * NCOUT + n) * NCIN + i];
    }
    if (tid < 16) mus[tid] = mu[tid];
    __syncthreads();

    unsigned xcc;
    asm volatile("s_getreg_b32 %0, hwreg(HW_REG_XCC_ID)" : "=s"(xcc));
    xcc &= 7;
    const int myb = (int)(xcc >> 1);

    const int lane = tid & 63;
    const int wv   = tid >> 6;
    const int m    = lane & 15;   // A-row (edge); D-col (channel) in epilogue
    const int q    = lane >> 4;

    for (int attempt = 0; attempt < 8; ++attempt) {
        const int qi = (int)((xcc + attempt) & 7);
        const int qb = qi >> 1;                       // batch served by queue qi
        const bool local = (qb == myb);               // block-uniform

        const _Float16* fbase = feat16 + (long)qb * NP * NCIN;
        float* obase = local ? (partial + (long)xcc * SLICE)
                             : (ovf + (long)qb * SLICE);
        const long ebq = (long)qb * NE + (long)(qi & 1) * (QCAP * 16);

        while (true) {
            // ---- block-level pop: ONE device-scope atomic per 128 edges
            if (tid == 0) sc_sh = atomicAdd(qcnt + qi * 16, 1);
            __syncthreads();
            const int sc = sc_sh;
            __syncthreads();                          // protect sc_sh reuse
            if (sc >= NSUPER) break;                  // block-uniform

            #pragma unroll 1
            for (int it = 0; it < SUPER / 4; ++it) {  // 2 iters per wave
                // INTERLEAVED chunk assignment: wave wv takes chunks
                // sc*8 + it*4 + wv -> 64-192 B scattered stream reads
                const int  c  = sc * SUPER + it * 4 + wv;
                const long e0 = ebq + (long)c * 16;   // this wave's 16 edges
                const long ge = e0 + m;
                const int  src = __builtin_nontemporal_load(edge_src + ge);

                // gather: one 64 B line per edge, L2-resident table
                half8 xh = *(const half8*)(fbase + (long)src * NCIN + q * 8);

                const float* ev = edge_vec + ge * 3;
                float vx = __builtin_nontemporal_load(ev + 0);
                float vy = __builtin_nontemporal_load(ev + 1);
                float vz = __builtin_nontemporal_load(ev + 2);
                // self-interaction zeroing in ref is a numeric no-op
                float r = sqrtf(vx * vx + vy * vy + vz * vz);

                float rbf[16];
                #pragma unroll
                for (int s = 0; s < 16; ++s) {
                    float d = r - mus[s];
                    rbf[s] = __expf(-GAMMA * d * d);
                }

                floatx4 accLo = {0.f, 0.f, 0.f, 0.f};   // channels 0..15
                floatx4 accHi = {0.f, 0.f, 0.f, 0.f};   // channels 16..31

                #pragma unroll
                for (int s = 0; s < 16; ++s) {
                    const _Float16 rh = (_Float16)rbf[s];
                    half8 a = xh * rh;                   // 4x v_pk_mul_f16
                    half8 b0 = *(const half8*)(wsw + ((s * 2 + 0) * 64 + lane) * 8);
                    half8 b1 = *(const half8*)(wsw + ((s * 2 + 1) * 64 + lane) * 8);
                    accLo = __builtin_amdgcn_mfma_f32_16x16x32_f16(a, b0, accLo, 0, 0, 0);
                    accHi = __builtin_amdgcn_mfma_f32_16x16x32_f16(a, b1, accHi, 0, 0, 0);
                }

                // Epilogue: lane holds D[row=q*4+rr][col=m]; 16 lanes cover
                // 16 consecutive channels -> coalesced 64 B atomic segments.
                if (local) {
                    #pragma unroll
                    for (int rr = 0; rr < 4; ++rr) {
                        const long e2  = e0 + q * 4 + rr;
                        const int  dst = __builtin_nontemporal_load(edge_dst + e2);
                        float* orow = obase + (long)dst * NCOUT;
                        __hip_atomic_fetch_add(orow + m,      accLo[rr],
                            __ATOMIC_RELAXED, __HIP_MEMORY_SCOPE_WORKGROUP);
                        __hip_atomic_fetch_add(orow + m + 16, accHi[rr],
                            __ATOMIC_RELAXED, __HIP_MEMORY_SCOPE_WORKGROUP);
                    }
                } else {
                    #pragma unroll
                    for (int rr = 0; rr < 4; ++rr) {
                        const long e2  = e0 + q * 4 + rr;
                        const int  dst = __builtin_nontemporal_load(edge_dst + e2);
                        float* orow = obase + (long)dst * NCOUT;
                        atomicAdd(orow + m,      accLo[rr]);
                        atomicAdd(orow + m + 16, accHi[rr]);
                    }
                }
            }
        }
    }
}

// ---------------------------------------------------------------------------
// Fallback A (ws >= 2 MB): round-5 kernel verbatim (best measured: 248 us).
// ---------------------------------------------------------------------------
__global__ __launch_bounds__(256, 4)
void pconv_f16_kernel(const _Float16* __restrict__ feat16,
                      const float* __restrict__ edge_vec,
                      const float* __restrict__ W,
                      const float* __restrict__ mu,
                      const int* __restrict__ edge_src,
                      const int* __restrict__ edge_dst,
                      const int* __restrict__ n_norm_p,
                      float* __restrict__ out)
{
    __shared__ _Float16 wsw[16 * 2 * 64 * 8];
    __shared__ float mus[16];

    const int tid = threadIdx.x;
    for (int idx = tid; idx < 16384; idx += 256) {
        int j = idx & 7;
        int l = (idx >> 3) & 63;
        int u = (idx >> 9) & 1;
        int s = idx >> 10;
        int n = (l & 15) + (u << 4);
        int i = ((l >> 4) << 3) | j;
        wsw[idx] = (_Float16)W[(s * NCOUT + n) * NCIN + i];
    }
    if (tid < 16) mus[tid] = mu[tid];
    __syncthreads();

    const int lane = tid & 63;
    const int wv   = tid >> 6;
    const int m    = lane & 15;
    const int q    = lane >> 4;

    const int nn = n_norm_p[0];
    const float scale = (nn > 0) ? rsqrtf((float)nn) : 1.0f;

    const int g    = blockIdx.x & 7;
    const int bb   = g >> 1;
    const int sub  = g & 1;
    const int bi   = blockIdx.x >> 3;

    const _Float16* fbase = feat16 + ((long)bb << 13) * NCIN;
    float* obase = out + ((long)bb << 13) * NCOUT;
    const long ebatch = (long)bb * NE;

    for (int i = bi; i < TILES_PER_BATCH / 2; i += 128) {
        const int  tloc  = (i << 1) + sub;
        const long ebase = ebatch + (long)tloc * 64 + (long)wv * 16;
        const long ge    = ebase + m;
        const int  src   = __builtin_nontemporal_load(edge_src + ge);

        half8 xh = *(const half8*)(fbase + (long)src * NCIN + q * 8);

        const float* ev = edge_vec + ge * 3;
        float vx = __builtin_nontemporal_load(ev + 0);
        float vy = __builtin_nontemporal_load(ev + 1);
        float vz = __builtin_nontemporal_load(ev + 2);
        float r = sqrtf(vx * vx + vy * vy + vz * vz);

        float rbf[16];
        #pragma unroll
        for (int s = 0; s < 16; ++s) {
            float d = r - mus[s];
            rbf[s] = __expf(-GAMMA * d * d);
        }

        floatx4 accLo = {0.f, 0.f, 0.f, 0.f};
        floatx4 accHi = {0.f, 0.f, 0.f, 0.f};

        #pragma unroll
        for (int s = 0; s < 16; ++s) {
            const _Float16 rh = (_Float16)rbf[s];
            half8 a = xh * rh;
            half8 b0 = *(const half8*)(wsw + ((s * 2 + 0) * 64 + lane) * 8);
            half8 b1 = *(const half8*)(wsw + ((s * 2 + 1) * 64 + lane) * 8);
            accLo = __builtin_amdgcn_mfma_f32_16x16x32_f16(a, b0, accLo, 0, 0, 0);
            accHi = __builtin_amdgcn_mfma_f32_16x16x32_f16(a, b1, accHi, 0, 0, 0);
        }

        #pragma unroll
        for (int rr = 0; rr < 4; ++rr) {
            const long e2  = ebase + q * 4 + rr;
            const int  dst = __builtin_nontemporal_load(edge_dst + e2);
            float* orow = obase + (long)dst * NCOUT;
            atomicAdd(orow + m,      accLo[rr] * scale);
            atomicAdd(orow + m + 16, accHi[rr] * scale);
        }
    }
}

// ---------------------------------------------------------------------------
// Fallback B (no workspace): round-3 kernel (f32 gathers).
// ---------------------------------------------------------------------------
__global__ __launch_bounds__(256, 4)
void pconv_mfma_kernel(const float* __restrict__ features,
                       const float* __restrict__ edge_vec,
                       const float* __restrict__ W,
                       const float* __restrict__ mu,
                       const int* __restrict__ edge_src,
                       const int* __restrict__ edge_dst,
                       const int* __restrict__ n_norm_p,
                       float* __restrict__ out)
{
    __shared__ _Float16 wsw[16 * 2 * 64 * 8];
    __shared__ float mus[16];

    const int tid = threadIdx.x;
    for (int idx = tid; idx < 16384; idx += 256) {
        int j = idx & 7;
        int l = (idx >> 3) & 63;
        int u = (idx >> 9) & 1;
        int s = idx >> 10;
        int n = (l & 15) + (u << 4);
        int i = ((l >> 4) << 3) | j;
        wsw[idx] = (_Float16)W[(s * NCOUT + n) * NCIN + i];
    }
    if (tid < 16) mus[tid] = mu[tid];
    __syncthreads();

    const int lane = tid & 63;
    const int wv   = tid >> 6;
    const int m    = lane & 15;
    const int q    = lane >> 4;

    const int nn = n_norm_p[0];
    const float scale = (nn > 0) ? rsqrtf((float)nn) : 1.0f;

    const int g    = blockIdx.x & 7;
    const int bb   = g >> 1;
    const int sub  = g & 1;
    const int bi   = blockIdx.x >> 3;

    const float* fbase = features + ((long)bb << 13) * NCIN;
    float* obase = out + ((long)bb << 13) * NCOUT;
    const long ebatch = (long)bb * NE;

    for (int i = bi; i < TILES_PER_BATCH / 2; i += 128) {
        const int  tloc  = (i << 1) + sub;
        const long ebase = ebatch + (long)tloc * 64 + (long)wv * 16;
        const long ge    = ebase + m;
        const int  src   = edge_src[ge];

        const float* xrow = fbase + (long)src * NCIN + q * 8;
        floatx4 xa = *(const floatx4*)(xrow);
        floatx4 xb = *(const floatx4*)(xrow + 4);

        const float* ev = edge_vec + ge * 3;
        float vx = ev[0], vy = ev[1], vz = ev[2];
        float r = sqrtf(vx * vx + vy * vy + vz * vz);

        float rbf[16];
        #pragma unroll
        for (int s = 0; s < 16; ++s) {
            float d = r - mus[s];
            rbf[s] = __expf(-GAMMA * d * d);
        }

        floatx4 accLo = {0.f, 0.f, 0.f, 0.f};
        floatx4 accHi = {0.f, 0.f, 0.f, 0.f};

        #pragma unroll
        for (int s = 0; s < 16; ++s) {
            const float rb = rbf[s];
            half8 a;
            a[0] = (_Float16)(rb * xa[0]);
            a[1] = (_Float16)(rb * xa[1]);
            a[2] = (_Float16)(rb * xa[2]);
            a[3] = (_Float16)(rb * xa[3]);
            a[4] = (_Float16)(rb * xb[0]);
            a[5] = (_Float16)(rb * xb[1]);
            a[6] = (_Float16)(rb * xb[2]);
            a[7] = (_Float16)(rb * xb[3]);
            half8 b0 = *(const half8*)(wsw + ((s * 2 + 0) * 64 + lane) * 8);
            half8 b1 = *(const half8*)(wsw + ((s * 2 + 1) * 64 + lane) * 8);
            accLo = __builtin_amdgcn_mfma_f32_16x16x32_f16(a, b0, accLo, 0, 0, 0);
            accHi = __builtin_amdgcn_mfma_f32_16x16x32_f16(a, b1, accHi, 0, 0, 0);
        }

        #pragma unroll
        for (int rr = 0; rr < 4; ++rr) {
            const long e2  = ebase + q * 4 + rr;
            const int  dst = edge_dst[e2];
            float* orow = obase + (long)dst * NCOUT;
            atomicAdd(orow + m,      accLo[rr] * scale);
            atomicAdd(orow + m + 16, accHi[rr] * scale);
        }
    }
}

extern "C" void kernel_launch(void* const* d_in, const int* in_sizes, int n_in,
                              void* d_out, int out_size, void* d_ws, size_t ws_size,
                              hipStream_t stream) {
    const float* features = (const float*)d_in[0];
    const float* edge_vec = (const float*)d_in[1];
    const float* W        = (const float*)d_in[2];
    const float* mu       = (const float*)d_in[3];
    const int*   edge_src = (const int*)d_in[4];
    const int*   edge_dst = (const int*)d_in[5];
    const int*   n_norm   = (const int*)d_in[6];
    float* out = (float*)d_out;

    // ws layout: partial[8][1MB] | ovf[4MB] | f16[2MB] | qcnt[4KB]
    const size_t part_bytes = (size_t)NXCD * SLICE * sizeof(float);  //  8 MB
    const size_t ovf_bytes  = (size_t)NOUT * sizeof(float);          //  4 MB
    const size_t f16_bytes  = (size_t)NFEAT * sizeof(_Float16);      //  2 MB
    const size_t q_bytes    = 4096;
    const size_t need_full  = part_bytes + ovf_bytes + f16_bytes + q_bytes;

    if (d_ws != nullptr && ws_size >= need_full) {
        char* ws = (char*)d_ws;
        float*    partial = (float*)ws;
        float*    ovf     = (float*)(ws + part_bytes);
        _Float16* f16t    = (_Float16*)(ws + part_bytes + ovf_bytes);
        int*      qcnt    = (int*)(ws + part_bytes + ovf_bytes + f16_bytes);

        prep_kernel<<<1024, 256, 0, stream>>>(features, f16t,
                                              (floatx4*)partial, qcnt);
        pconv_queue_kernel<<<1024, 256, 0, stream>>>(f16t, edge_vec, W, mu,
                                                     edge_src, edge_dst,
                                                     partial, ovf, qcnt);
        reduce_kernel<<<1024, 256, 0, stream>>>((const floatx4*)partial,
                                                (const floatx4*)ovf,
                                                n_norm, (floatx4*)out);
    } else if (d_ws != nullptr && ws_size >= f16_bytes) {
        hipMemsetAsync(out, 0, (size_t)out_size * sizeof(float), stream);
        _Float16* f16t = (_Float16*)d_ws;
        cvt_f16_kernel<<<NFEAT / 8 / 256, 256, 0, stream>>>(features, f16t);
        pconv_f16_kernel<<<1024, 256, 0, stream>>>(f16t, edge_vec, W, mu,
                                                   edge_src, edge_dst, n_norm, out);
    } else {
        hipMemsetAsync(out, 0, (size_t)out_size * sizeof(float), stream);
        pconv_mfma_kernel<<<1024, 256, 0, stream>>>(features, edge_vec, W, mu,
                                                    edge_src, edge_dst, n_norm, out);
    }
}

// Round 10
// 334.631 us; speedup vs baseline: 1.0841x; 1.0841x over previous
//
#include <hip/hip_runtime.h>
#include <cmath>

// Problem constants (from reference)
#define NB 4
#define NP 8192            // 2^13 points per batch
#define NE 262144          // 2^18 edges per batch
#define NCIN 32
#define NCOUT 32
#define NH 16
#define GAMMA 4.0f
#define NFEAT (NB * NP * NCIN)      // 1,048,576 floats (4 MB)
#define NOUT  (NB * NP * NCOUT)     // 1,048,576 floats (4 MB)
#define TILES_PER_BATCH (NE / 64)

// Binning geometry
#define PREB 512                    // bin_kernel blocks (slabs)
#define SLAB 2048                   // edges per slab (128 slabs/batch)
#define NREG 32                     // dst regions per batch (256 points each)
#define RPTS 256                    // points per region
#define CAP  112                    // records per (slab, region); lambda=64, 6-sigma
#define NBIN (NB * NREG)            // 128 bins
#define BPB  4                      // main blocks per bin -> grid 512 = 2/CU

typedef _Float16 half8 __attribute__((ext_vector_type(8)));
typedef float floatx4 __attribute__((ext_vector_type(4)));

// ---------------------------------------------------------------------------
// Prep: zero the 4 partial buffers (16 MB) + build f16 feature table.
// ---------------------------------------------------------------------------
__global__ __launch_bounds__(256)
void prep_kernel(const float* __restrict__ features,
                 _Float16* __restrict__ f16t,
                 floatx4* __restrict__ partial4)
{
    const int i = blockIdx.x * blockDim.x + threadIdx.x;    // 0 .. 262143
    const floatx4 z = {0.f, 0.f, 0.f, 0.f};
    #pragma unroll
    for (int p = 0; p < BPB; ++p)
        partial4[(long)p * (NOUT / 4) + i] = z;

    if (i < NFEAT / 8) {                        // f32 -> f16 table
        const floatx4* src = (const floatx4*)features + (long)i * 2;
        floatx4 v0 = src[0], v1 = src[1];
        half8 h;
        h[0] = (_Float16)v0[0]; h[1] = (_Float16)v0[1];
        h[2] = (_Float16)v0[2]; h[3] = (_Float16)v0[3];
        h[4] = (_Float16)v1[0]; h[5] = (_Float16)v1[1];
        h[6] = (_Float16)v1[2]; h[7] = (_Float16)v1[3];
        *((half8*)f16t + i) = h;
    }
}

// cvt-only variant for the fallback path.
__global__ __launch_bounds__(256)
void cvt_f16_kernel(const float* __restrict__ features, _Float16* __restrict__ f16t)
{
    const int i = blockIdx.x * blockDim.x + threadIdx.x;    // 0 .. 131071
    const floatx4* src = (const floatx4*)features + (long)i * 2;
    floatx4 v0 = src[0], v1 = src[1];
    half8 h;
    h[0] = (_Float16)v0[0]; h[1] = (_Float16)v0[1];
    h[2] = (_Float16)v0[2]; h[3] = (_Float16)v0[3];
    h[4] = (_Float16)v1[0]; h[5] = (_Float16)v1[1];
    h[6] = (_Float16)v1[2]; h[7] = (_Float16)v1[3];
    *((half8*)f16t + i) = h;
}

// ---------------------------------------------------------------------------
// Bin pass: slab b (2048 contiguous edges, within one batch) appends each
// edge's record {r, src | dstLow<<13} to segment (b, dst>>8). Counters live
// in LDS -> ZERO global atomics. Writes ~17 MB, reads ~20 MB, streaming.
// ---------------------------------------------------------------------------
__global__ __launch_bounds__(256)
void bin_kernel(const float* __restrict__ edge_vec,
                const int* __restrict__ edge_src,
                const int* __restrict__ edge_dst,
                uint2* __restrict__ rec,
                int* __restrict__ scnt)
{
    __shared__ int lcnt[NREG];
    const int tid = threadIdx.x;
    if (tid < NREG) lcnt[tid] = 0;
    __syncthreads();

    const long e0 = (long)blockIdx.x * SLAB;
    const long segbase = (long)blockIdx.x * NREG;

    #pragma unroll 1
    for (int k = 0; k < SLAB / 256; ++k) {
        const long e = e0 + k * 256 + tid;              // coalesced
        const float* ev = edge_vec + e * 3;
        const float vx = ev[0], vy = ev[1], vz = ev[2];
        // self-interaction zeroing in ref is a numeric no-op (r<1e-10 -> r=0)
        const float r = sqrtf(vx * vx + vy * vy + vz * vz);
        const int src = edge_src[e];
        const int dst = edge_dst[e];
        const int lb  = dst >> 8;                       // region 0..31
        const int pos = atomicAdd(&lcnt[lb], 1);        // LDS atomic
        if (pos < CAP) {
            uint2 rc;
            rc.x = __float_as_uint(r);
            rc.y = (unsigned)src | ((unsigned)(dst & 255) << 13);
            rec[(segbase + lb) * CAP + pos] = rc;
        }
    }
    __syncthreads();
    if (tid < NREG) scnt[segbase + tid] = min(lcnt[tid], CAP);
}

// ---------------------------------------------------------------------------
// Main kernel: bin (batch,region) owns a 32 KB LDS accumulator. Block
// (bin, part) drains 32 of the bin's 128 slab-segments through the MFMA
// core, scatters D-rows into LDS (ds_add_f32 - no fabric RMW), then writes
// the region ONCE to partial[part]. Zero global atomics anywhere.
//
// Rationale: rounds 0-9 proved per-edge memory scatter (any scope, any
// affinity, any rate) saturates ~3.6 TB/s of fabric traffic; only LDS-side
// accumulation removes it.
//
// GEMM view: msg[e, o] = sum_k Z[e,k] * W2T[k,o],  k = h*32 + i, K = 512
//   Z[e, h*32+i] = rbf_h(e) * x_src[e][i]
// MFMA f32_16x16x32_f16 layouts (HW-verified, learn_hip m89/m91):
//   A: lane holds A[m=lane&15][k_local=(lane>>4)*8+j], j=0..7
//   B: lane holds B[k_local][n=lane&15]
//   D: lane holds D[row=(lane>>4)*4+rr][col=m]
// Masked rows (chunk tail): rbf=0 -> A-row=0 -> D-row=0 -> LDS add of 0.
// ---------------------------------------------------------------------------
__global__ __launch_bounds__(512, 4)
void pconv_bin_kernel(const _Float16* __restrict__ feat16,
                      const float* __restrict__ W,
                      const float* __restrict__ mu,
                      const uint2* __restrict__ rec,
                      const int* __restrict__ scnt,
                      float* __restrict__ partial)
{
    __shared__ _Float16 wsw[16 * 2 * 64 * 8];      // 32 KiB, B-fragment order
    __shared__ float acc_lds[RPTS * NCOUT];        // 32 KiB region accumulator
    __shared__ float mus[16];

    const int tid = threadIdx.x;                   // 0..511
    for (int idx = tid; idx < 16384; idx += 512) {
        int j = idx & 7;
        int l = (idx >> 3) & 63;
        int u = (idx >> 9) & 1;
        int s = idx >> 10;
        int n = (l & 15) + (u << 4);               // output channel o
        int i = ((l >> 4) << 3) | j;               // input channel
        wsw[idx] = (_Float16)W[(s * NCOUT + n) * NCIN + i];
    }
    for (int idx = tid; idx < RPTS * NCOUT; idx += 512)
        acc_lds[idx] = 0.f;
    if (tid < 16) mus[tid] = mu[tid];
    __syncthreads();

    const int bin   = blockIdx.x >> 2;             // 0..127
    const int part  = blockIdx.x & 3;
    const int batch = bin >> 5;
    const int lbin  = bin & 31;

    const int lane = tid & 63;
    const int wv   = tid >> 6;                     // 0..7
    const int m    = lane & 15;                    // edge row / channel col
    const int q    = lane >> 4;

    const _Float16* fbase = feat16 + (long)batch * NP * NCIN;

    #pragma unroll 1
    for (int s4 = 0; s4 < 4; ++s4) {
        // this wave's segment: slab pb of this batch
        const int pb   = batch * 128 + part * 32 + wv * 4 + s4;
        const long segi = (long)pb * NREG + lbin;
        const int cnt  = scnt[segi];
        const uint2* rbase = rec + segi * CAP;

        #pragma unroll 1
        for (int c0 = 0; c0 < cnt; c0 += 16) {
            const bool act = (c0 + m) < cnt;
            const uint2 rc = rbase[act ? (c0 + m) : 0];
            const float r  = act ? __uint_as_float(rc.x) : 1e9f;
            const int  src = (int)(rc.y & 8191u);

            // gather: one 64 B line per edge from the 512 KB f16 table
            half8 xh = *(const half8*)(fbase + (long)src * NCIN + q * 8);

            float rbf[16];
            #pragma unroll
            for (int s = 0; s < 16; ++s) {
                float d = r - mus[s];
                rbf[s] = __expf(-GAMMA * d * d);   // masked: exp(-4e18) = 0
            }

            floatx4 accLo = {0.f, 0.f, 0.f, 0.f};  // channels 0..15
            floatx4 accHi = {0.f, 0.f, 0.f, 0.f};  // channels 16..31

            #pragma unroll
            for (int s = 0; s < 16; ++s) {
                const _Float16 rh = (_Float16)rbf[s];
                half8 a = xh * rh;                 // 4x v_pk_mul_f16
                half8 b0 = *(const half8*)(wsw + ((s * 2 + 0) * 64 + lane) * 8);
                half8 b1 = *(const half8*)(wsw + ((s * 2 + 1) * 64 + lane) * 8);
                accLo = __builtin_amdgcn_mfma_f32_16x16x32_f16(a, b0, accLo, 0, 0, 0);
                accHi = __builtin_amdgcn_mfma_f32_16x16x32_f16(a, b1, accHi, 0, 0, 0);
            }

            // Epilogue: D[row=q*4+rr][col=m] -> LDS accumulator (ds_add_f32).
            // dstLow of row (q*4+rr) comes from that edge's lane via shuffle.
            #pragma unroll
            for (int rr = 0; rr < 4; ++rr) {
                const unsigned y2 = (unsigned)__shfl((int)rc.y, (q << 2) + rr, 64);
                const int dl = (int)((y2 >> 13) & 255u);
                atomicAdd(&acc_lds[dl * NCOUT + m],      accLo[rr]);
                atomicAdd(&acc_lds[dl * NCOUT + m + 16], accHi[rr]);
            }
        }
    }
    __syncthreads();

    // flush: region written once, plain vectorized stores
    floatx4* pdst = (floatx4*)(partial + (long)part * NOUT
                               + ((long)batch * NP + (long)lbin * RPTS) * NCOUT);
    const floatx4* asrc = (const floatx4*)acc_lds;
    for (int idx = tid; idx < RPTS * NCOUT / 4; idx += 512)
        pdst[idx] = asrc[idx];
}

// ---------------------------------------------------------------------------
// Reduce: out = scale * sum_p partial[p].  20 MB streaming.
// ---------------------------------------------------------------------------
__global__ __launch_bounds__(256)
void reduce_kernel(const floatx4* __restrict__ partial4,
                   const int* __restrict__ n_norm_p,
                   floatx4* __restrict__ out4)
{
    const int i = blockIdx.x * blockDim.x + threadIdx.x;    // 0 .. 262143
    const int nn = n_norm_p[0];
    const float scale = (nn > 0) ? rsqrtf((float)nn) : 1.0f;
    floatx4 s = {0.f, 0.f, 0.f, 0.f};
    #pragma unroll
    for (int p = 0; p < BPB; ++p)
        s += partial4[(long)p * (NOUT / 4) + i];
    out4[i] = s * scale;
}

// ---------------------------------------------------------------------------
// Fallback A (ws >= 2 MB): round-5 kernel verbatim (best measured: 248 us).
// ---------------------------------------------------------------------------
__global__ __launch_bounds__(256, 4)
void pconv_f16_kernel(const _Float16* __restrict__ feat16,
                      const float* __restrict__ edge_vec,
                      const float* __restrict__ W,
                      const float* __restrict__ mu,
                      const int* __restrict__ edge_src,
                      const int* __restrict__ edge_dst,
                      const int* __restrict__ n_norm_p,
                      float* __restrict__ out)
{
    __shared__ _Float16 wsw[16 * 2 * 64 * 8];
    __shared__ float mus[16];

    const int tid = threadIdx.x;
    for (int idx = tid; idx < 16384; idx += 256) {
        int j = idx & 7;
        int l = (idx >> 3) & 63;
        int u = (idx >> 9) & 1;
        int s = idx >> 10;
        int n = (l & 15) + (u << 4);
        int i = ((l >> 4) << 3) | j;
        wsw[idx] = (_Float16)W[(s * NCOUT + n) * NCIN + i];
    }
    if (tid < 16) mus[tid] = mu[tid];
    __syncthreads();

    const int lane = tid & 63;
    const int wv   = tid >> 6;
    const int m    = lane & 15;
    const int q    = lane >> 4;

    const int nn = n_norm_p[0];
    const float scale = (nn > 0) ? rsqrtf((float)nn) : 1.0f;

    const int g    = blockIdx.x & 7;
    const int bb   = g >> 1;
    const int sub  = g & 1;
    const int bi   = blockIdx.x >> 3;

    const _Float16* fbase = feat16 + ((long)bb << 13) * NCIN;
    float* obase = out + ((long)bb << 13) * NCOUT;
    const long ebatch = (long)bb * NE;

    for (int i = bi; i < TILES_PER_BATCH / 2; i += 128) {
        const int  tloc  = (i << 1) + sub;
        const long ebase = ebatch + (long)tloc * 64 + (long)wv * 16;
        const long ge    = ebase + m;
        const int  src   = __builtin_nontemporal_load(edge_src + ge);

        half8 xh = *(const half8*)(fbase + (long)src * NCIN + q * 8);

        const float* ev = edge_vec + ge * 3;
        float vx = __builtin_nontemporal_load(ev + 0);
        float vy = __builtin_nontemporal_load(ev + 1);
        float vz = __builtin_nontemporal_load(ev + 2);
        float r = sqrtf(vx * vx + vy * vy + vz * vz);

        float rbf[16];
        #pragma unroll
        for (int s = 0; s < 16; ++s) {
            float d = r - mus[s];
            rbf[s] = __expf(-GAMMA * d * d);
        }

        floatx4 accLo = {0.f, 0.f, 0.f, 0.f};
        floatx4 accHi = {0.f, 0.f, 0.f, 0.f};

        #pragma unroll
        for (int s = 0; s < 16; ++s) {
            const _Float16 rh = (_Float16)rbf[s];
            half8 a = xh * rh;
            half8 b0 = *(const half8*)(wsw + ((s * 2 + 0) * 64 + lane) * 8);
            half8 b1 = *(const half8*)(wsw + ((s * 2 + 1) * 64 + lane) * 8);
            accLo = __builtin_amdgcn_mfma_f32_16x16x32_f16(a, b0, accLo, 0, 0, 0);
            accHi = __builtin_amdgcn_mfma_f32_16x16x32_f16(a, b1, accHi, 0, 0, 0);
        }

        #pragma unroll
        for (int rr = 0; rr < 4; ++rr) {
            const long e2  = ebase + q * 4 + rr;
            const int  dst = __builtin_nontemporal_load(edge_dst + e2);
            float* orow = obase + (long)dst * NCOUT;
            atomicAdd(orow + m,      accLo[rr] * scale);
            atomicAdd(orow + m + 16, accHi[rr] * scale);
        }
    }
}

// ---------------------------------------------------------------------------
// Fallback B (no workspace): round-3 kernel (f32 gathers).
// ---------------------------------------------------------------------------
__global__ __launch_bounds__(256, 4)
void pconv_mfma_kernel(const float* __restrict__ features,
                       const float* __restrict__ edge_vec,
                       const float* __restrict__ W,
                       const float* __restrict__ mu,
                       const int* __restrict__ edge_src,
                       const int* __restrict__ edge_dst,
                       const int* __restrict__ n_norm_p,
                       float* __restrict__ out)
{
    __shared__ _Float16 wsw[16 * 2 * 64 * 8];
    __shared__ float mus[16];

    const int tid = threadIdx.x;
    for (int idx = tid; idx < 16384; idx += 256) {
        int j = idx & 7;
        int l = (idx >> 3) & 63;
        int u = (idx >> 9) & 1;
        int s = idx >> 10;
        int n = (l & 15) + (u << 4);
        int i = ((l >> 4) << 3) | j;
        wsw[idx] = (_Float16)W[(s * NCOUT + n) * NCIN + i];
    }
    if (tid < 16) mus[tid] = mu[tid];
    __syncthreads();

    const int lane = tid & 63;
    const int wv   = tid >> 6;
    const int m    = lane & 15;
    const int q    = lane >> 4;

    const int nn = n_norm_p[0];
    const float scale = (nn > 0) ? rsqrtf((float)nn) : 1.0f;

    const int g    = blockIdx.x & 7;
    const int bb   = g >> 1;
    const int sub  = g & 1;
    const int bi   = blockIdx.x >> 3;

    const float* fbase = features + ((long)bb << 13) * NCIN;
    float* obase = out + ((long)bb << 13) * NCOUT;
    const long ebatch = (long)bb * NE;

    for (int i = bi; i < TILES_PER_BATCH / 2; i += 128) {
        const int  tloc  = (i << 1) + sub;
        const long ebase = ebatch + (long)tloc * 64 + (long)wv * 16;
        const long ge    = ebase + m;
        const int  src   = edge_src[ge];

        const float* xrow = fbase + (long)src * NCIN + q * 8;
        floatx4 xa = *(const floatx4*)(xrow);
        floatx4 xb = *(const floatx4*)(xrow + 4);

        const float* ev = edge_vec + ge * 3;
        float vx = ev[0], vy = ev[1], vz = ev[2];
        float r = sqrtf(vx * vx + vy * vy + vz * vz);

        float rbf[16];
        #pragma unroll
        for (int s = 0; s < 16; ++s) {
            float d = r - mus[s];
            rbf[s] = __expf(-GAMMA * d * d);
        }

        floatx4 accLo = {0.f, 0.f, 0.f, 0.f};
        floatx4 accHi = {0.f, 0.f, 0.f, 0.f};

        #pragma unroll
        for (int s = 0; s < 16; ++s) {
            const float rb = rbf[s];
            half8 a;
            a[0] = (_Float16)(rb * xa[0]);
            a[1] = (_Float16)(rb * xa[1]);
            a[2] = (_Float16)(rb * xa[2]);
            a[3] = (_Float16)(rb * xa[3]);
            a[4] = (_Float16)(rb * xb[0]);
            a[5] = (_Float16)(rb * xb[1]);
            a[6] = (_Float16)(rb * xb[2]);
            a[7] = (_Float16)(rb * xb[3]);
            half8 b0 = *(const half8*)(wsw + ((s * 2 + 0) * 64 + lane) * 8);
            half8 b1 = *(const half8*)(wsw + ((s * 2 + 1) * 64 + lane) * 8);
            accLo = __builtin_amdgcn_mfma_f32_16x16x32_f16(a, b0, accLo, 0, 0, 0);
            accHi = __builtin_amdgcn_mfma_f32_16x16x32_f16(a, b1, accHi, 0, 0, 0);
        }

        #pragma unroll
        for (int rr = 0; rr < 4; ++rr) {
            const long e2  = ebase + q * 4 + rr;
            const int  dst = edge_dst[e2];
            float* orow = obase + (long)dst * NCOUT;
            atomicAdd(orow + m,      accLo[rr] * scale);
            atomicAdd(orow + m + 16, accHi[rr] * scale);
        }
    }
}

extern "C" void kernel_launch(void* const* d_in, const int* in_sizes, int n_in,
                              void* d_out, int out_size, void* d_ws, size_t ws_size,
                              hipStream_t stream) {
    const float* features = (const float*)d_in[0];
    const float* edge_vec = (const float*)d_in[1];
    const float* W        = (const float*)d_in[2];
    const float* mu       = (const float*)d_in[3];
    const int*   edge_src = (const int*)d_in[4];
    const int*   edge_dst = (const int*)d_in[5];
    const int*   n_norm   = (const int*)d_in[6];
    float* out = (float*)d_out;

    // ws layout: partial[4][4MB] | f16[2MB] | rec[512*32*112*8B] | scnt[64KB]
    const size_t part_bytes = (size_t)BPB * NOUT * sizeof(float);        // 16 MB
    const size_t f16_bytes  = (size_t)NFEAT * sizeof(_Float16);          //  2 MB
    const size_t rec_bytes  = (size_t)PREB * NREG * CAP * sizeof(uint2); // 14 MB
    const size_t cnt_bytes  = (size_t)PREB * NREG * sizeof(int);         // 64 KB
    const size_t need_full  = part_bytes + f16_bytes + rec_bytes + cnt_bytes;

    if (d_ws != nullptr && ws_size >= need_full) {
        char* ws = (char*)d_ws;
        float*    partial = (float*)ws;
        _Float16* f16t    = (_Float16*)(ws + part_bytes);
        uint2*    rec     = (uint2*)(ws + part_bytes + f16_bytes);
        int*      scnt    = (int*)(ws + part_bytes + f16_bytes + rec_bytes);

        prep_kernel<<<1024, 256, 0, stream>>>(features, f16t, (floatx4*)partial);
        bin_kernel<<<PREB, 256, 0, stream>>>(edge_vec, edge_src, edge_dst,
                                             rec, scnt);
        pconv_bin_kernel<<<NBIN * BPB, 512, 0, stream>>>(f16t, W, mu,
                                                         rec, scnt, partial);
        reduce_kernel<<<1024, 256, 0, stream>>>((const floatx4*)partial,
                                                n_norm, (floatx4*)out);
    } else if (d_ws != nullptr && ws_size >= f16_bytes) {
        hipMemsetAsync(out, 0, (size_t)out_size * sizeof(float), stream);
        _Float16* f16t = (_Float16*)d_ws;
        cvt_f16_kernel<<<NFEAT / 8 / 256, 256, 0, stream>>>(features, f16t);
        pconv_f16_kernel<<<1024, 256, 0, stream>>>(f16t, edge_vec, W, mu,
                                                   edge_src, edge_dst, n_norm, out);
    } else {
        hipMemsetAsync(out, 0, (size_t)out_size * sizeof(float), stream);
        pconv_mfma_kernel<<<1024, 256, 0, stream>>>(features, edge_vec, W, mu,
                                                    edge_src, edge_dst, n_norm, out);
    }
}

// Round 11
// 218.050 us; speedup vs baseline: 1.6637x; 1.5347x over previous
//
#include <hip/hip_runtime.h>
#include <cmath>

// Problem constants (from reference)
#define NB 4
#define NP 8192            // 2^13 points per batch
#define NE 262144          // 2^18 edges per batch
#define NCIN 32
#define NCOUT 32
#define NH 16
#define GAMMA 4.0f
#define NFEAT (NB * NP * NCIN)      // 1,048,576 floats (4 MB)
#define TILES_PER_BATCH (NE / 64)

// Src-binning geometry
#define NSLAB 512                   // bin blocks; slab = 2048 contiguous edges
#define SLAB  2048
#define SREG  8                     // src regions per batch (1024 points each)
#define RPTS  1024                  // points per src region (64 KB f16 in LDS)
#define CAP   384                   // records per (slab, region); mean 256, +8.5 sigma
#define OVCAP 8192                  // overflow list capacity

typedef _Float16 half8 __attribute__((ext_vector_type(8)));
typedef float floatx4 __attribute__((ext_vector_type(4)));

// ---------------------------------------------------------------------------
// Bin pass: slab = 2048 contiguous edges (one batch). Append record
// {r, srcLow | dst<<10} to segment (slab, src>>10). Counters in LDS ->
// zero global atomics on the hot path. CAP spill -> global overflow list.
// ---------------------------------------------------------------------------
__global__ __launch_bounds__(256)
void bin_kernel(const float* __restrict__ edge_vec,
                const int* __restrict__ edge_src,
                const int* __restrict__ edge_dst,
                uint2* __restrict__ rec,
                int* __restrict__ scnt,
                int* __restrict__ ovfcnt,
                uint4* __restrict__ ovfrec)
{
    __shared__ int lcnt[SREG];
    const int tid = threadIdx.x;
    if (tid < SREG) lcnt[tid] = 0;
    __syncthreads();

    const long e0 = (long)blockIdx.x * SLAB;
    const int batch = (int)(e0 >> 18);
    const long segbase = (long)blockIdx.x * SREG;

    #pragma unroll 1
    for (int k = 0; k < SLAB / 256; ++k) {
        const long e = e0 + k * 256 + tid;              // coalesced
        const float* ev = edge_vec + e * 3;
        const float vx = ev[0], vy = ev[1], vz = ev[2];
        // self-interaction zeroing in ref is a numeric no-op (r<1e-10 -> r=0)
        const float r = sqrtf(vx * vx + vy * vy + vz * vz);
        const int src = edge_src[e];
        const int dst = edge_dst[e];
        const int rg  = src >> 10;                      // src region 0..7
        const int pos = atomicAdd(&lcnt[rg], 1);        // LDS atomic
        if (pos < CAP) {
            uint2 rc;
            rc.x = __float_as_uint(r);
            rc.y = (unsigned)(src & 1023) | ((unsigned)dst << 10);
            rec[(segbase + rg) * CAP + pos] = rc;
        } else {
            const int op = atomicAdd(ovfcnt, 1);        // ~never taken
            if (op < OVCAP) {
                uint4 rc;
                rc.x = __float_as_uint(r);
                rc.y = (unsigned)src;
                rc.z = (unsigned)dst;
                rc.w = (unsigned)batch;
                ovfrec[op] = rc;
            }
        }
    }
    __syncthreads();
    if (tid < SREG) scnt[segbase + tid] = min(lcnt[tid], CAP);
}

// ---------------------------------------------------------------------------
// Main kernel: block = (batch, src-region, sub). The region's 1024 feature
// rows live in LDS as f16 (64 KB) -> the per-edge gather is an LDS read,
// ZERO fabric traffic. (R5 vs R10 counter subtraction proved the ~450 MB
// FETCH was the global gather, not the atomics.) Scatter: R5-proven device
// atomics straight to out.
//
// LDS: wsw 32 KB + flds 64 KB = 96 KB -> 1 block/CU (512 thr, 8 waves).
//
// GEMM view: msg[e, o] = sum_k Z[e,k] * W2T[k,o],  k = h*32 + i, K = 512
//   Z[e, h*32+i] = rbf_h(e) * x_src[e][i]
// MFMA f32_16x16x32_f16 layouts (HW-verified, learn_hip m89/m91):
//   A: lane holds A[m=lane&15][k_local=(lane>>4)*8+j], j=0..7
//   B: lane holds B[k_local][n=lane&15]
//   D: lane holds D[row=(lane>>4)*4+rr][col=m]
// Masked tail rows: r=1e9 -> rbf=0 -> D-row=0 -> atomicAdd of 0 (harmless).
// ---------------------------------------------------------------------------
__global__ __launch_bounds__(512, 2)
void pconv_src_kernel(const float* __restrict__ features,
                      const float* __restrict__ W,
                      const float* __restrict__ mu,
                      const int* __restrict__ n_norm_p,
                      const uint2* __restrict__ rec,
                      const int* __restrict__ scnt,
                      float* __restrict__ out)
{
    __shared__ _Float16 wsw[16 * 2 * 64 * 8];      // 32 KiB, B-fragment order
    __shared__ _Float16 flds[RPTS * NCIN];         // 64 KiB region features
    __shared__ float mus[16];

    const int tid = threadIdx.x;                   // 0..511
    for (int idx = tid; idx < 16384; idx += 512) {
        int j = idx & 7;
        int l = (idx >> 3) & 63;
        int u = (idx >> 9) & 1;
        int s = idx >> 10;
        int n = (l & 15) + (u << 4);               // output channel o
        int i = ((l >> 4) << 3) | j;               // input channel
        wsw[idx] = (_Float16)W[(s * NCOUT + n) * NCIN + i];
    }
    if (tid < 16) mus[tid] = mu[tid];

    const int bin   = blockIdx.x >> 3;             // 0..31 = batch*8 + region
    const int sub   = blockIdx.x & 7;
    const int batch = bin >> 3;
    const int reg   = bin & 7;

    // stage this region's features: f32 global -> f16 LDS (128 KB read)
    const float* fb = features + ((long)batch * NP + (long)reg * RPTS) * NCIN;
    for (int j = tid; j < RPTS * NCIN / 8; j += 512) {
        const floatx4* s = (const floatx4*)fb + (long)j * 2;
        floatx4 v0 = s[0], v1 = s[1];
        half8 h;
        h[0] = (_Float16)v0[0]; h[1] = (_Float16)v0[1];
        h[2] = (_Float16)v0[2]; h[3] = (_Float16)v0[3];
        h[4] = (_Float16)v1[0]; h[5] = (_Float16)v1[1];
        h[6] = (_Float16)v1[2]; h[7] = (_Float16)v1[3];
        *((half8*)flds + j) = h;
    }
    __syncthreads();

    const int lane = tid & 63;
    const int wv   = tid >> 6;                     // 0..7
    const int m    = lane & 15;                    // edge row / channel col
    const int q    = lane >> 4;

    const int nn = n_norm_p[0];
    const float scale = (nn > 0) ? rsqrtf((float)nn) : 1.0f;
    float* obase = out + ((long)batch * NP) * NCOUT;

    #pragma unroll 1
    for (int sl = 0; sl < 2; ++sl) {
        // this wave's slab: 16 slabs per sub, 2 per wave
        const int slab = batch * 128 + sub * 16 + wv * 2 + sl;
        const long segi = (long)slab * SREG + reg;
        const int cnt = scnt[segi];
        const uint2* rb = rec + segi * CAP;

        #pragma unroll 1
        for (int c0 = 0; c0 < cnt; c0 += 16) {
            const bool act = (c0 + m) < cnt;
            const uint2 rc = rb[act ? (c0 + m) : 0];
            const float r  = act ? __uint_as_float(rc.x) : 1e9f;
            const int  sL  = (int)(rc.y & 1023u);

            // gather from LDS: one ds_read_b128 per lane, no fabric traffic
            half8 xh = *(const half8*)(flds + sL * NCIN + q * 8);

            float rbf[16];
            #pragma unroll
            for (int s = 0; s < 16; ++s) {
                float d = r - mus[s];
                rbf[s] = __expf(-GAMMA * d * d);   // masked -> 0
            }

            floatx4 accLo = {0.f, 0.f, 0.f, 0.f};  // channels 0..15
            floatx4 accHi = {0.f, 0.f, 0.f, 0.f};  // channels 16..31

            #pragma unroll
            for (int s = 0; s < 16; ++s) {
                const _Float16 rh = (_Float16)rbf[s];
                half8 a = xh * rh;                 // 4x v_pk_mul_f16
                half8 b0 = *(const half8*)(wsw + ((s * 2 + 0) * 64 + lane) * 8);
                half8 b1 = *(const half8*)(wsw + ((s * 2 + 1) * 64 + lane) * 8);
                accLo = __builtin_amdgcn_mfma_f32_16x16x32_f16(a, b0, accLo, 0, 0, 0);
                accHi = __builtin_amdgcn_mfma_f32_16x16x32_f16(a, b1, accHi, 0, 0, 0);
            }

            // Epilogue: D[row=q*4+rr][col=m]; 16 lanes cover 16 consecutive
            // channels -> coalesced 64 B atomic segments (R5-proven path).
            #pragma unroll
            for (int rr = 0; rr < 4; ++rr) {
                const unsigned y2 = (unsigned)__shfl((int)rc.y, (q << 2) + rr, 64);
                const int dst = (int)((y2 >> 10) & 8191u);
                float* orow = obase + (long)dst * NCOUT;
                atomicAdd(orow + m,      accLo[rr] * scale);
                atomicAdd(orow + m + 16, accHi[rr] * scale);
            }
        }
    }
}

// ---------------------------------------------------------------------------
// Overflow cleanup: scalar per-edge compute for CAP-spilled records
// (expected count: 0; probability ~1e-7). f32 math, atomic scatter.
// ---------------------------------------------------------------------------
__global__ __launch_bounds__(256)
void ovf_kernel(const float* __restrict__ features,
                const float* __restrict__ W,
                const float* __restrict__ mu,
                const int* __restrict__ n_norm_p,
                const int* __restrict__ ovfcnt,
                const uint4* __restrict__ ovfrec,
                float* __restrict__ out)
{
    const int n = min(ovfcnt[0], OVCAP);
    if (n == 0) return;
    const int nn = n_norm_p[0];
    const float scale = (nn > 0) ? rsqrtf((float)nn) : 1.0f;

    for (int idx = blockIdx.x * blockDim.x + threadIdx.x; idx < n * NCOUT;
         idx += gridDim.x * blockDim.x) {
        const int e = idx >> 5, o = idx & 31;
        const uint4 rc = ovfrec[e];
        const float r = __uint_as_float(rc.x);
        const int src = (int)rc.y, dst = (int)rc.z, b = (int)rc.w;
        const float* x = features + ((long)b * NP + src) * NCIN;
        float acc = 0.f;
        for (int h = 0; h < NH; ++h) {
            float d = r - mu[h];
            float rb = __expf(-GAMMA * d * d);
            float s = 0.f;
            for (int i = 0; i < NCIN; ++i)
                s += W[(h * NCOUT + o) * NCIN + i] * x[i];
            acc += rb * s;
        }
        atomicAdd(out + ((long)b * NP + dst) * NCOUT + o, acc * scale);
    }
}

// ---------------------------------------------------------------------------
// Fallback A (ws >= 2 MB): round-5 pipeline verbatim (best measured: 248 us).
// ---------------------------------------------------------------------------
__global__ __launch_bounds__(256)
void cvt_f16_kernel(const float* __restrict__ features, _Float16* __restrict__ f16t)
{
    const int i = blockIdx.x * blockDim.x + threadIdx.x;    // 0 .. 131071
    const floatx4* src = (const floatx4*)features + (long)i * 2;
    floatx4 v0 = src[0], v1 = src[1];
    half8 h;
    h[0] = (_Float16)v0[0]; h[1] = (_Float16)v0[1];
    h[2] = (_Float16)v0[2]; h[3] = (_Float16)v0[3];
    h[4] = (_Float16)v1[0]; h[5] = (_Float16)v1[1];
    h[6] = (_Float16)v1[2]; h[7] = (_Float16)v1[3];
    *((half8*)f16t + i) = h;
}

__global__ __launch_bounds__(256, 4)
void pconv_f16_kernel(const _Float16* __restrict__ feat16,
                      const float* __restrict__ edge_vec,
                      const float* __restrict__ W,
                      const float* __restrict__ mu,
                      const int* __restrict__ edge_src,
                      const int* __restrict__ edge_dst,
                      const int* __restrict__ n_norm_p,
                      float* __restrict__ out)
{
    __shared__ _Float16 wsw[16 * 2 * 64 * 8];
    __shared__ float mus[16];

    const int tid = threadIdx.x;
    for (int idx = tid; idx < 16384; idx += 256) {
        int j = idx & 7;
        int l = (idx >> 3) & 63;
        int u = (idx >> 9) & 1;
        int s = idx >> 10;
        int n = (l & 15) + (u << 4);
        int i = ((l >> 4) << 3) | j;
        wsw[idx] = (_Float16)W[(s * NCOUT + n) * NCIN + i];
    }
    if (tid < 16) mus[tid] = mu[tid];
    __syncthreads();

    const int lane = tid & 63;
    const int wv   = tid >> 6;
    const int m    = lane & 15;
    const int q    = lane >> 4;

    const int nn = n_norm_p[0];
    const float scale = (nn > 0) ? rsqrtf((float)nn) : 1.0f;

    const int g    = blockIdx.x & 7;
    const int bb   = g >> 1;
    const int sub  = g & 1;
    const int bi   = blockIdx.x >> 3;

    const _Float16* fbase = feat16 + ((long)bb << 13) * NCIN;
    float* obase = out + ((long)bb << 13) * NCOUT;
    const long ebatch = (long)bb * NE;

    for (int i = bi; i < TILES_PER_BATCH / 2; i += 128) {
        const int  tloc  = (i << 1) + sub;
        const long ebase = ebatch + (long)tloc * 64 + (long)wv * 16;
        const long ge    = ebase + m;
        const int  src   = __builtin_nontemporal_load(edge_src + ge);

        half8 xh = *(const half8*)(fbase + (long)src * NCIN + q * 8);

        const float* ev = edge_vec + ge * 3;
        float vx = __builtin_nontemporal_load(ev + 0);
        float vy = __builtin_nontemporal_load(ev + 1);
        float vz = __builtin_nontemporal_load(ev + 2);
        float r = sqrtf(vx * vx + vy * vy + vz * vz);

        float rbf[16];
        #pragma unroll
        for (int s = 0; s < 16; ++s) {
            float d = r - mus[s];
            rbf[s] = __expf(-GAMMA * d * d);
        }

        floatx4 accLo = {0.f, 0.f, 0.f, 0.f};
        floatx4 accHi = {0.f, 0.f, 0.f, 0.f};

        #pragma unroll
        for (int s = 0; s < 16; ++s) {
            const _Float16 rh = (_Float16)rbf[s];
            half8 a = xh * rh;
            half8 b0 = *(const half8*)(wsw + ((s * 2 + 0) * 64 + lane) * 8);
            half8 b1 = *(const half8*)(wsw + ((s * 2 + 1) * 64 + lane) * 8);
            accLo = __builtin_amdgcn_mfma_f32_16x16x32_f16(a, b0, accLo, 0, 0, 0);
            accHi = __builtin_amdgcn_mfma_f32_16x16x32_f16(a, b1, accHi, 0, 0, 0);
        }

        #pragma unroll
        for (int rr = 0; rr < 4; ++rr) {
            const long e2  = ebase + q * 4 + rr;
            const int  dst = __builtin_nontemporal_load(edge_dst + e2);
            float* orow = obase + (long)dst * NCOUT;
            atomicAdd(orow + m,      accLo[rr] * scale);
            atomicAdd(orow + m + 16, accHi[rr] * scale);
        }
    }
}

// ---------------------------------------------------------------------------
// Fallback B (no workspace): round-3 kernel (f32 gathers).
// ---------------------------------------------------------------------------
__global__ __launch_bounds__(256, 4)
void pconv_mfma_kernel(const float* __restrict__ features,
                       const float* __restrict__ edge_vec,
                       const float* __restrict__ W,
                       const float* __restrict__ mu,
                       const int* __restrict__ edge_src,
                       const int* __restrict__ edge_dst,
                       const int* __restrict__ n_norm_p,
                       float* __restrict__ out)
{
    __shared__ _Float16 wsw[16 * 2 * 64 * 8];
    __shared__ float mus[16];

    const int tid = threadIdx.x;
    for (int idx = tid; idx < 16384; idx += 256) {
        int j = idx & 7;
        int l = (idx >> 3) & 63;
        int u = (idx >> 9) & 1;
        int s = idx >> 10;
        int n = (l & 15) + (u << 4);
        int i = ((l >> 4) << 3) | j;
        wsw[idx] = (_Float16)W[(s * NCOUT + n) * NCIN + i];
    }
    if (tid < 16) mus[tid] = mu[tid];
    __syncthreads();

    const int lane = tid & 63;
    const int wv   = tid >> 6;
    const int m    = lane & 15;
    const int q    = lane >> 4;

    const int nn = n_norm_p[0];
    const float scale = (nn > 0) ? rsqrtf((float)nn) : 1.0f;

    const int g    = blockIdx.x & 7;
    const int bb   = g >> 1;
    const int sub  = g & 1;
    const int bi   = blockIdx.x >> 3;

    const float* fbase = features + ((long)bb << 13) * NCIN;
    float* obase = out + ((long)bb << 13) * NCOUT;
    const long ebatch = (long)bb * NE;

    for (int i = bi; i < TILES_PER_BATCH / 2; i += 128) {
        const int  tloc  = (i << 1) + sub;
        const long ebase = ebatch + (long)tloc * 64 + (long)wv * 16;
        const long ge    = ebase + m;
        const int  src   = edge_src[ge];

        const float* xrow = fbase + (long)src * NCIN + q * 8;
        floatx4 xa = *(const floatx4*)(xrow);
        floatx4 xb = *(const floatx4*)(xrow + 4);

        const float* ev = edge_vec + ge * 3;
        float vx = ev[0], vy = ev[1], vz = ev[2];
        float r = sqrtf(vx * vx + vy * vy + vz * vz);

        float rbf[16];
        #pragma unroll
        for (int s = 0; s < 16; ++s) {
            float d = r - mus[s];
            rbf[s] = __expf(-GAMMA * d * d);
        }

        floatx4 accLo = {0.f, 0.f, 0.f, 0.f};
        floatx4 accHi = {0.f, 0.f, 0.f, 0.f};

        #pragma unroll
        for (int s = 0; s < 16; ++s) {
            const float rb = rbf[s];
            half8 a;
            a[0] = (_Float16)(rb * xa[0]);
            a[1] = (_Float16)(rb * xa[1]);
            a[2] = (_Float16)(rb * xa[2]);
            a[3] = (_Float16)(rb * xa[3]);
            a[4] = (_Float16)(rb * xb[0]);
            a[5] = (_Float16)(rb * xb[1]);
            a[6] = (_Float16)(rb * xb[2]);
            a[7] = (_Float16)(rb * xb[3]);
            half8 b0 = *(const half8*)(wsw + ((s * 2 + 0) * 64 + lane) * 8);
            half8 b1 = *(const half8*)(wsw + ((s * 2 + 1) * 64 + lane) * 8);
            accLo = __builtin_amdgcn_mfma_f32_16x16x32_f16(a, b0, accLo, 0, 0, 0);
            accHi = __builtin_amdgcn_mfma_f32_16x16x32_f16(a, b1, accHi, 0, 0, 0);
        }

        #pragma unroll
        for (int rr = 0; rr < 4; ++rr) {
            const long e2  = ebase + q * 4 + rr;
            const int  dst = edge_dst[e2];
            float* orow = obase + (long)dst * NCOUT;
            atomicAdd(orow + m,      accLo[rr] * scale);
            atomicAdd(orow + m + 16, accHi[rr] * scale);
        }
    }
}

extern "C" void kernel_launch(void* const* d_in, const int* in_sizes, int n_in,
                              void* d_out, int out_size, void* d_ws, size_t ws_size,
                              hipStream_t stream) {
    const float* features = (const float*)d_in[0];
    const float* edge_vec = (const float*)d_in[1];
    const float* W        = (const float*)d_in[2];
    const float* mu       = (const float*)d_in[3];
    const int*   edge_src = (const int*)d_in[4];
    const int*   edge_dst = (const int*)d_in[5];
    const int*   n_norm   = (const int*)d_in[6];
    float* out = (float*)d_out;

    // harness poisons d_out; all paths accumulate via atomics
    hipMemsetAsync(out, 0, (size_t)out_size * sizeof(float), stream);

    // ws layout: rec[512*8*CAP] (8 B) | scnt[4096] | ovfcnt | ovfrec[8192*16B]
    const size_t rec_bytes = (size_t)NSLAB * SREG * CAP * sizeof(uint2); // 12.6 MB
    const size_t cnt_bytes = (size_t)NSLAB * SREG * sizeof(int);         // 16 KB
    const size_t ovc_bytes = 64;
    const size_t ovr_bytes = (size_t)OVCAP * sizeof(uint4);              // 128 KB
    const size_t need_full = rec_bytes + cnt_bytes + ovc_bytes + ovr_bytes;
    const size_t f16_bytes = (size_t)NFEAT * sizeof(_Float16);           // 2 MB

    if (d_ws != nullptr && ws_size >= need_full) {
        char* ws = (char*)d_ws;
        uint2* rec    = (uint2*)ws;
        int*   scnt   = (int*)(ws + rec_bytes);
        int*   ovfcnt = (int*)(ws + rec_bytes + cnt_bytes);
        uint4* ovfrec = (uint4*)(ws + rec_bytes + cnt_bytes + ovc_bytes);

        hipMemsetAsync(ovfcnt, 0, sizeof(int), stream);
        bin_kernel<<<NSLAB, 256, 0, stream>>>(edge_vec, edge_src, edge_dst,
                                              rec, scnt, ovfcnt, ovfrec);
        pconv_src_kernel<<<NB * SREG * 8, 512, 0, stream>>>(
            features, W, mu, n_norm, rec, scnt, out);
        ovf_kernel<<<64, 256, 0, stream>>>(features, W, mu, n_norm,
                                           ovfcnt, ovfrec, out);
    } else if (d_ws != nullptr && ws_size >= f16_bytes) {
        _Float16* f16t = (_Float16*)d_ws;
        cvt_f16_kernel<<<NFEAT / 8 / 256, 256, 0, stream>>>(features, f16t);
        pconv_f16_kernel<<<1024, 256, 0, stream>>>(f16t, edge_vec, W, mu,
                                                   edge_src, edge_dst, n_norm, out);
    } else {
        pconv_mfma_kernel<<<1024, 256, 0, stream>>>(features, edge_vec, W, mu,
                                                    edge_src, edge_dst, n_norm, out);
    }
}